// Round 2
// baseline (192.428 us; speedup 1.0000x reference)
//
#include <hip/hip_runtime.h>
#include <hip/hip_bf16.h>

#define MARGIN 0.2f
#define EPS 1e-8f
#define D 128

// One thread per triplet: gather 3 rows (float4 x 32), compute both distances,
// hinge losses, then block-reduce (total, active_count) and atomicAdd into acc.
__global__ __launch_bounds__(256) void triplet_loss_kernel(
    const float* __restrict__ batch,
    const float* __restrict__ beta,
    const int* __restrict__ labels,
    const int* __restrict__ triplets,
    float* __restrict__ acc,   // acc[0]=total, acc[1]=pair_count
    int T)
{
    int t = blockIdx.x * blockDim.x + threadIdx.x;

    float pos = 0.0f, neg = 0.0f, cnt = 0.0f;
    if (t < T) {
        int ai = triplets[3 * t + 0];
        int pi = triplets[3 * t + 1];
        int ni = triplets[3 * t + 2];

        const float4* __restrict__ a = (const float4*)(batch + (size_t)ai * D);
        const float4* __restrict__ p = (const float4*)(batch + (size_t)pi * D);
        const float4* __restrict__ n = (const float4*)(batch + (size_t)ni * D);

        float dap = 0.0f, dan = 0.0f;
#pragma unroll 8
        for (int i = 0; i < D / 4; ++i) {
            float4 av = a[i];
            float4 pv = p[i];
            float4 nv = n[i];
            float dx;
            dx = av.x - pv.x; dap = fmaf(dx, dx, dap);
            dx = av.y - pv.y; dap = fmaf(dx, dx, dap);
            dx = av.z - pv.z; dap = fmaf(dx, dx, dap);
            dx = av.w - pv.w; dap = fmaf(dx, dx, dap);
            dx = av.x - nv.x; dan = fmaf(dx, dx, dan);
            dx = av.y - nv.y; dan = fmaf(dx, dx, dan);
            dx = av.z - nv.z; dan = fmaf(dx, dx, dan);
            dx = av.w - nv.w; dan = fmaf(dx, dx, dan);
        }

        float d_ap = sqrtf(dap + EPS);
        float d_an = sqrtf(dan + EPS);
        float b = beta[labels[ai]];

        pos = fmaxf(d_ap - b + MARGIN, 0.0f);
        neg = fmaxf(b - d_an + MARGIN, 0.0f);
        cnt = (pos > 0.0f || neg > 0.0f) ? 1.0f : 0.0f;
    }

    float total = pos + neg;

    // wave64 butterfly reduce
#pragma unroll
    for (int off = 32; off > 0; off >>= 1) {
        total += __shfl_down(total, off, 64);
        cnt   += __shfl_down(cnt,   off, 64);
    }

    __shared__ float s_tot[4];
    __shared__ float s_cnt[4];
    int wid  = threadIdx.x >> 6;
    int lane = threadIdx.x & 63;
    if (lane == 0) { s_tot[wid] = total; s_cnt[wid] = cnt; }
    __syncthreads();

    if (threadIdx.x == 0) {
        float bt = s_tot[0] + s_tot[1] + s_tot[2] + s_tot[3];
        float bc = s_cnt[0] + s_cnt[1] + s_cnt[2] + s_cnt[3];
        atomicAdd(&acc[0], bt);
        atomicAdd(&acc[1], bc);
    }
}

__global__ void finalize_kernel(const float* __restrict__ acc, float* __restrict__ out)
{
    float total = acc[0];
    float cnt   = acc[1];
    // loss = where(count == 0, total, total / max(count, 1))
    out[0] = (cnt == 0.0f) ? total : total / fmaxf(cnt, 1.0f);
}

extern "C" void kernel_launch(void* const* d_in, const int* in_sizes, int n_in,
                              void* d_out, int out_size, void* d_ws, size_t ws_size,
                              hipStream_t stream)
{
    const float* batch    = (const float*)d_in[0];   // (16384, 128) f32
    const float* beta     = (const float*)d_in[1];   // (1000,) f32
    const int*   labels   = (const int*)d_in[2];     // (16384,) i32
    const int*   triplets = (const int*)d_in[3];     // (T, 3) i32
    float* out = (float*)d_out;

    int T = in_sizes[3] / 3;

    float* acc = (float*)d_ws;  // acc[0]=total, acc[1]=count (poisoned each call)
    hipMemsetAsync(acc, 0, 2 * sizeof(float), stream);

    int block = 256;
    int grid = (T + block - 1) / block;
    triplet_loss_kernel<<<grid, block, 0, stream>>>(batch, beta, labels, triplets, acc, T);
    finalize_kernel<<<1, 1, 0, stream>>>(acc, out);
}